// Round 9
// baseline (154.802 us; speedup 1.0000x reference)
//
#include <hip/hip_runtime.h>
#include <hip/hip_fp16.h>

// SSIM loss, fused, MFMA-blur v9. fp32 in [16,3,512,512], fp32 scalar out.
// Round-8 postmortem: residency-quantization theory dead (occ ~30% at LDS
// limits 4/5/6 blocks alike). New clue: VGPR_Count=56 -> a 2-deep raw
// prefetch (needs 32 regs for 2 sets + ~50 others) CANNOT be live -> the
// compiler sank load8 to its use site (branchy `if(j&1)/if(j<5)` loop with
// #pragma unroll 1 let it), so every step pays full ~900cy HBM latency
// with only ~10 resident waves. Fix: FULLY UNROLL the 8-step loop -> all
// conditionals compile-time, A/B ping-pong straight-line, scheduler hoists
// each load batch 2 steps ahead with counted vmcnt. Pure scheduling change
// on v8 (zero dataflow delta).
// Ring: [qty][slot-block][col][8 slots] halves, 24576B;
// addr(q,c,s) = q*6144 + (s>>3)*1024 + c*16 + (s&7)*2. b128 reads and b64
// writes start at bank 4c%32 -> 2-way aliased (free).
// Wave-private ring (col 16wv+r15) -> barrier-free main loop (v5-verified);
// MFMA blurs (v_mfma_f32_16x16x32_f16, fp32 accum):
//   h: D[r][c] = sum_k plane[r][16wv+k] * w[k-c-3]   (A from regs)
//   v: D[c][r] = sum_k ring[c][16j+k]   * w[k-r]
// fp16 weight-sum drift folded into scaled C1/C2.

#define WIDTH  512
#define HEIGHT 512
#define TW 64
#define SH 128
#define RING 48                  // logical ring rows (mod-48), 6 blocks of 8
#define TILES_X 8
#define TILES_Y (HEIGHT / SH)    // 4
#define PLANES 48
#define NBLK (TILES_X * TILES_Y * PLANES)   // 1536
#define NPIXF 12582912.0f

typedef _Float16 half8_t __attribute__((ext_vector_type(8)));
typedef float f32x4_t __attribute__((ext_vector_type(4)));
typedef unsigned int u32x4_t __attribute__((ext_vector_type(4)));

// banded weight lookup; 0 outside [0,10]. Symmetric kernel.
__device__ __forceinline__ float wsel(int i) {
    unsigned a = (unsigned)i;
    float r = 0.f;
    if (a == 5u)              r = 0.26601168f;
    if (a == 4u || a == 6u)   r = 0.21300566f;
    if (a == 3u || a == 7u)   r = 0.10936069f;
    if (a == 2u || a == 8u)   r = 0.03600077f;
    if (a == 1u || a == 9u)   r = 0.00759881f;
    if (a == 0u || a == 10u)  r = 0.00102839f;
    return r;
}

__device__ __forceinline__ unsigned cvt2(float a, float b) {
    return __builtin_bit_cast(unsigned, __floats2half2_rn(a, b));
}

__global__ __launch_bounds__(256, 4)
void ssim_main(const float* __restrict__ pred,
               const float* __restrict__ tgt,
               float* __restrict__ partial) {
    // ring: [qty][slot-block][col][slot-in-block] halves; 24576 B total.
    __shared__ __align__(16) __half s_ring[4][RING / 8][TW][8];
    __shared__ float s_red[4];

    const int tid  = threadIdx.x;
    const int wv   = tid >> 6;          // wave id = 16-col output chunk
    const int lane = tid & 63;
    const int r15  = lane & 15;
    const int g4   = lane >> 4;
    const int x0 = blockIdx.x * TW;
    const int y0 = blockIdx.y * SH;
    const size_t plane_off = (size_t)blockIdx.z * (WIDTH * HEIGHT);
    const float* P = pred + plane_off;
    const float* T = tgt + plane_off;

    // this thread's fragment window: global x base (multiple of 8)
    const int gxb  = x0 - 8 + (wv << 4) + (g4 << 3);
    const int colA = (wv << 4) + r15;                  // ring column (wave-private)

    // fp16 weight-sum per pass (compile-time): acc scale a = s1^2.
    const float s1 = 2.f * ((float)(_Float16)0.00102839f + (float)(_Float16)0.00759881f
                   + (float)(_Float16)0.03600077f + (float)(_Float16)0.10936069f
                   + (float)(_Float16)0.21300566f) + (float)(_Float16)0.26601168f;
    const float a   = s1 * s1;
    const float C1A = a * a * 1e-4f;
    const float C2A = a * a * 9e-4f;

    // Banded weight fragments (B operand: col = lane&15, k = (lane>>4)*8+j).
    half8_t Bh, Bv;
#pragma unroll
    for (int jj = 0; jj < 8; ++jj) {
        int k = g4 * 8 + jj;
        Bv[jj] = (_Float16)wsel(k - r15);        // Wv[k][r] = w[k-r]
        Bh[jj] = (_Float16)wsel(k - r15 - 3);    // Wh[k][c] = w[k-c-3]
    }

    // ---- raw loads: 8 px at row gybase+r15, cols gxb..gxb+7 (clamped) ----
    auto load8 = [&](int gybase, float4& p0, float4& p1,
                     float4& t0, float4& t1) {
        int gy = gybase + r15;
        if (gy < 0) gy = 0;
        if (gy > HEIGHT - 1) gy = HEIGHT - 1;
        int gxc = gxb;
        if (gxc < 0) gxc = 0;
        if (gxc > WIDTH - 8) gxc = WIDTH - 8;
        const float* pr = P + ((size_t)gy << 9) + gxc;
        const float* tr = T + ((size_t)gy << 9) + gxc;
        p0 = *(const float4*)pr; p1 = *(const float4*)(pr + 4);
        t0 = *(const float4*)tr; t1 = *(const float4*)(tr + 4);
    };

    // ---- ewise in regs: build 4 A-fragments (p,t,u,v), fp32 math ----
    auto make_frags = [&](int gybase, float4 pv0, float4 pv1,
                          float4 tv0, float4 tv1, u32x4_t* F) {
        int gy = gybase + r15;
        const bool ok = ((unsigned)gy < (unsigned)HEIGHT) &&
                        ((unsigned)gxb <= (unsigned)(WIDTH - 8));
        if (!ok) {
            pv0.x = pv0.y = pv0.z = pv0.w = 0.f;
            pv1.x = pv1.y = pv1.z = pv1.w = 0.f;
            tv0.x = tv0.y = tv0.z = tv0.w = 0.f;
            tv1.x = tv1.y = tv1.z = tv1.w = 0.f;
        }
        float u0 = fmaf(pv0.x, pv0.x, tv0.x * tv0.x), v0 = pv0.x * tv0.x;
        float u1 = fmaf(pv0.y, pv0.y, tv0.y * tv0.y), v1 = pv0.y * tv0.y;
        float u2 = fmaf(pv0.z, pv0.z, tv0.z * tv0.z), v2 = pv0.z * tv0.z;
        float u3 = fmaf(pv0.w, pv0.w, tv0.w * tv0.w), v3 = pv0.w * tv0.w;
        float u4 = fmaf(pv1.x, pv1.x, tv1.x * tv1.x), v4 = pv1.x * tv1.x;
        float u5 = fmaf(pv1.y, pv1.y, tv1.y * tv1.y), v5 = pv1.y * tv1.y;
        float u6 = fmaf(pv1.z, pv1.z, tv1.z * tv1.z), v6 = pv1.z * tv1.z;
        float u7 = fmaf(pv1.w, pv1.w, tv1.w * tv1.w), v7 = pv1.w * tv1.w;
        u32x4_t Pu, Tu, Uu, Vu;
        Pu[0] = cvt2(pv0.x, pv0.y); Pu[1] = cvt2(pv0.z, pv0.w);
        Pu[2] = cvt2(pv1.x, pv1.y); Pu[3] = cvt2(pv1.z, pv1.w);
        Tu[0] = cvt2(tv0.x, tv0.y); Tu[1] = cvt2(tv0.z, tv0.w);
        Tu[2] = cvt2(tv1.x, tv1.y); Tu[3] = cvt2(tv1.z, tv1.w);
        Uu[0] = cvt2(u0, u1); Uu[1] = cvt2(u2, u3);
        Uu[2] = cvt2(u4, u5); Uu[3] = cvt2(u6, u7);
        Vu[0] = cvt2(v0, v1); Vu[1] = cvt2(v2, v3);
        Vu[2] = cvt2(v4, v5); Vu[3] = cvt2(v6, v7);
        F[0] = Pu; F[1] = Tu; F[2] = Uu; F[3] = Vu;
    };

    // ---- h-blur MFMA from register fragments; pack D rows to uint2 ----
    auto hcompute = [&](const u32x4_t* F, uint2* dpk) {
#pragma unroll
        for (int q = 0; q < 4; ++q) {
            f32x4_t z = {0.f, 0.f, 0.f, 0.f};
            f32x4_t d = __builtin_amdgcn_mfma_f32_16x16x32_f16(
                __builtin_bit_cast(half8_t, F[q]), Bh, z, 0, 0, 0);
            dpk[q].x = cvt2(d[0], d[1]);
            dpk[q].y = cvt2(d[2], d[3]);
        }
    };
    // lane's 4 D rows (slots s0..s0+3, s0 mult of 4 -> stays inside one
    // 8-slot block) = one aligned 8B ds_write_b64
    auto hstore = [&](const uint2* dpk, int relbase) {
        int s0 = relbase + 4 * g4;
        if (s0 >= 96) s0 -= 96; else if (s0 >= 48) s0 -= 48;
        const int sb = s0 >> 3, si = s0 & 7;
#pragma unroll
        for (int q = 0; q < 4; ++q)
            *(uint2*)&s_ring[q][sb][colA][si] = dpk[q];
    };

    float lsum = 0.f;

    // ---- v-blur MFMA + SSIM. Reads rel 16j..16j+31 (k>=26 zero-weight;
    // all slots finite: wave-private zero-init or this wave's data). ----
    auto vblur = [&](int jstep) {
        int sg = 16 * jstep + (g4 << 3);
        if (sg >= 96) sg -= 96; else if (sg >= 48) sg -= 48;
        const int sb = sg >> 3;              // sg mult of 8: one whole block
        f32x4_t acc[4];
#pragma unroll
        for (int q = 0; q < 4; ++q) {
            u32x4_t ra = *(const u32x4_t*)&s_ring[q][sb][colA][0];
            f32x4_t z = {0.f, 0.f, 0.f, 0.f};
            acc[q] = __builtin_amdgcn_mfma_f32_16x16x32_f16(
                __builtin_bit_cast(half8_t, ra), Bv, z, 0, 0, 0);
        }
#pragma unroll
        for (int r = 0; r < 4; ++r) {
            float mp = acc[0][r], mt = acc[1][r];       // scaled by a
            float U  = acc[2][r], V  = acc[3][r];
            float mpt  = mp * mt;                        // a^2 * true
            float B2   = fmaf(mp, mp, mt * mt);          // a^2 * true
            float S    = fmaf(a, V, -mpt);               // a^2 * sigma_pt
            float Ssum = fmaf(a, U, -B2);                // a^2 * (sp+st)
            float num = fmaf(2.f, mpt, C1A) * fmaf(2.f, S, C2A);
            float den = (B2 + C1A) * (Ssum + C2A);
            lsum += __fdividef(num, den);
        }
    };

    // ---- Prologue (all wave-local; no barriers) ----
    float4 Ap0, Ap1, At0, At1;      // raw set A (even gens)
    float4 Bp0, Bp1, Bt0, Bt1;      // raw set B (odd gens)
    load8(y0 - 5, Ap0, Ap1, At0, At1);    // gen -2: rel 0..15
    load8(y0 + 7, Bp0, Bp1, Bt0, Bt1);    // gen -1: rel 12..27
    {
        // zero own wave's 16 columns: lane (g4,r15) zeros qty g4, col colA,
        // all 6 slot-blocks (16B each) -> wave-private, no barrier needed.
        u32x4_t z4 = {0u, 0u, 0u, 0u};
#pragma unroll
        for (int i = 0; i < RING / 8; ++i)
            *(u32x4_t*)&s_ring[g4][i][colA][0] = z4;
    }
    u32x4_t F2[4], F1[4];
    uint2 d2[4], d1[4];
    make_frags(y0 - 5, Ap0, Ap1, At0, At1, F2);
    load8(y0 + 23, Ap0, Ap1, At0, At1);   // gen 0 -> set A
    hcompute(F2, d2);
    make_frags(y0 + 7, Bp0, Bp1, Bt0, Bt1, F1);
    load8(y0 + 39, Bp0, Bp1, Bt0, Bt1);   // gen 1 -> set B
    hcompute(F1, d1);
    hstore(d2, 0);                         // rel 0..15 (after own-col zero)
    hstore(d1, 12);                        // rel 12..27 (12..15 same values)

    // ---- Main loop: FULLY UNROLLED 8 steps, NO barriers ----
    // Straight-line code: loads for gen j+2 hoistable 2 steps ahead of
    // their consumer with counted vmcnt; A/B ping-pong is compile-time.
#pragma unroll
    for (int j = 0; j < 8; ++j) {
        vblur(j);                          // reads rel 16j..16j+31 (own cols)
        u32x4_t F[4];
        uint2 dpk[4];
        if (j < 7) {
            if (j & 1) make_frags(y0 + 16 * j + 23, Bp0, Bp1, Bt0, Bt1, F);
            else       make_frags(y0 + 16 * j + 23, Ap0, Ap1, At0, At1, F);
        }
        if (j < 5) {
            if (j & 1) load8(y0 + 16 * (j + 2) + 23, Bp0, Bp1, Bt0, Bt1);
            else       load8(y0 + 16 * (j + 2) + 23, Ap0, Ap1, At0, At1);
        }
        if (j < 7) {
            hcompute(F, dpk);
            hstore(dpk, 16 * j + 28);      // rel 16j+28..43 (own columns)
        }
    }

    // ---- Block reduction -> one partial per block (the ONLY barrier) ----
#pragma unroll
    for (int off = 32; off > 0; off >>= 1) lsum += __shfl_down(lsum, off);
    if ((tid & 63) == 0) s_red[tid >> 6] = lsum;
    __syncthreads();
    if (tid == 0) {
        partial[(blockIdx.z * TILES_Y + blockIdx.y) * TILES_X + blockIdx.x] =
            s_red[0] + s_red[1] + s_red[2] + s_red[3];
    }
}

__global__ __launch_bounds__(256)
void ssim_final(const float* __restrict__ partial, float* __restrict__ out) {
    __shared__ float s_red[4];
    float s = 0.f;
    for (int i = threadIdx.x; i < NBLK; i += 256) s += partial[i];
#pragma unroll
    for (int off = 32; off > 0; off >>= 1) s += __shfl_down(s, off);
    if ((threadIdx.x & 63) == 0) s_red[threadIdx.x >> 6] = s;
    __syncthreads();
    if (threadIdx.x == 0) {
        float total = s_red[0] + s_red[1] + s_red[2] + s_red[3];
        out[0] = 1.0f - total / NPIXF;
    }
}

extern "C" void kernel_launch(void* const* d_in, const int* in_sizes, int n_in,
                              void* d_out, int out_size, void* d_ws, size_t ws_size,
                              hipStream_t stream) {
    const float* pred = (const float*)d_in[0];
    const float* tgt  = (const float*)d_in[1];
    float* partial = (float*)d_ws;   // NBLK floats, fully rewritten each call

    dim3 grid(TILES_X, TILES_Y, PLANES);
    ssim_main<<<grid, dim3(256), 0, stream>>>(pred, tgt, partial);
    ssim_final<<<1, dim3(256), 0, stream>>>(partial, (float*)d_out);
}

// Round 10
// 133.489 us; speedup vs baseline: 1.1597x; 1.1597x over previous
//
#include <hip/hip_runtime.h>
#include <hip/hip_fp16.h>

// SSIM loss, fused, MFMA-blur v10. fp32 in [16,3,512,512], fp32 scalar out.
// Round-9 postmortem: full unroll = scratch spills (WRITE 49MB), regression.
// Scoreboard: v2 (barrier-paced, planes-LDS, 42us) beats ALL barrier-free
// register-fragment variants (47-55us). Mechanism: VGPR_Count 44-56 in every
// "prefetch" variant -> compiler SINKS reg-dest global loads to use sites
// when control flow allows; only v2's __syncthreads pins the issue point
// (loads can't cross a barrier). v10 = v2 structure + 2 verified upgrades:
//  (1) 2-deep A/B raw prefetch, pinned by barriers: load(j+2) issued at
//      region-2 start of step j, consumed region 1 of step j+2 -> ~2 steps
//      (~1500cy) of cover > ~900cy HBM latency. Tell: VGPR ~70.
//  (2) sub-tiled ring [4][6][64][8] (v8-verified, 24.6KB) + planes padded
//      80->88 halves (read stride 176B -> 2-way banks). LDS 35.9KB, 4 blk/CU.
// Step j: {E(j): ewise gen j -> planes} bar {load(j+2); H(j): planes->MFMA->
// ring; V(j): ring->MFMA->SSIM} bar.   (v2-verified region structure;
// H(j) writes rel 16j+28..43, V(j) reads them only at zero-weight k>=26.)
// MFMA blurs (v_mfma_f32_16x16x32_f16, fp32 accum):
//   h: D[r][c] = sum_k plane[r][16wv+k] * w[k-c-3]
//   v: D[c][r] = sum_k ring[c][16j+k]   * w[k-r]
// fp16 weight-sum drift folded into scaled C1/C2.

#define WIDTH  512
#define HEIGHT 512
#define TW 64
#define SH 128
#define RING 48                  // logical ring rows (mod-48), 6 blocks of 8
#define TILES_X 8
#define TILES_Y (HEIGHT / SH)    // 4
#define PLANES 48
#define NBLK (TILES_X * TILES_Y * PLANES)   // 1536
#define NPIXF 12582912.0f

typedef _Float16 half8_t __attribute__((ext_vector_type(8)));
typedef float f32x4_t __attribute__((ext_vector_type(4)));
typedef unsigned int u32x4_t __attribute__((ext_vector_type(4)));

// banded weight lookup; 0 outside [0,10]. Symmetric kernel.
__device__ __forceinline__ float wsel(int i) {
    unsigned a = (unsigned)i;
    float r = 0.f;
    if (a == 5u)              r = 0.26601168f;
    if (a == 4u || a == 6u)   r = 0.21300566f;
    if (a == 3u || a == 7u)   r = 0.10936069f;
    if (a == 2u || a == 8u)   r = 0.03600077f;
    if (a == 1u || a == 9u)   r = 0.00759881f;
    if (a == 0u || a == 10u)  r = 0.00102839f;
    return r;
}

__device__ __forceinline__ unsigned cvt2(float a, float b) {
    return __builtin_bit_cast(unsigned, __floats2half2_rn(a, b));
}

__global__ __launch_bounds__(256, 4)
void ssim_main(const float* __restrict__ pred,
               const float* __restrict__ tgt,
               float* __restrict__ partial) {
    __shared__ __align__(16) __half s_ring[4][RING / 8][TW][8];  // 24576 B
    __shared__ __align__(16) __half s_pl[4][16][88];             // 11264 B
    __shared__ float s_red[4];

    const int tid  = threadIdx.x;
    const int wv   = tid >> 6;          // wave id = 16-col output chunk
    const int lane = tid & 63;
    const int r15  = lane & 15;
    const int g4   = lane >> 4;
    const int x0 = blockIdx.x * TW;
    const int y0 = blockIdx.y * SH;
    const size_t plane_off = (size_t)blockIdx.z * (WIDTH * HEIGHT);
    const float* P = pred + plane_off;
    const float* T = tgt + plane_off;
    const bool x_int = (x0 >= 8) && (x0 + TW + 8 <= WIDTH);

    const int colA = (wv << 4) + r15;   // ring column (wave-private)

    // fp16 weight-sum per pass (compile-time): acc scale a = s1^2.
    const float s1 = 2.f * ((float)(_Float16)0.00102839f + (float)(_Float16)0.00759881f
                   + (float)(_Float16)0.03600077f + (float)(_Float16)0.10936069f
                   + (float)(_Float16)0.21300566f) + (float)(_Float16)0.26601168f;
    const float a   = s1 * s1;
    const float C1A = a * a * 1e-4f;
    const float C2A = a * a * 9e-4f;

    // Banded weight fragments (B operand: col = lane&15, k = (lane>>4)*8+j).
    half8_t Bh, Bv;
#pragma unroll
    for (int jj = 0; jj < 8; ++jj) {
        int k = g4 * 8 + jj;
        Bv[jj] = (_Float16)wsel(k - r15);        // Wv[k][r] = w[k-r]
        Bh[jj] = (_Float16)wsel(k - r15 - 3);    // Wh[k][c] = w[k-c-3]
    }

    // Per-thread raw quads: quad0 for all, quad1 for tid<64 (cols 64..79).
    const int  erow0 = tid >> 4, ecq0 = tid & 15;
    const bool e2    = tid < 64;
    const int  erow1 = tid >> 2, ecq1 = 16 + (tid & 3);

    auto ldquad = [&](int gybase, int row, int cq, float4& p, float4& t) {
        int gy = gybase + row;
        if (gy < 0) gy = 0;
        if (gy > HEIGHT - 1) gy = HEIGHT - 1;
        int gx = x0 - 8 + cq * 4;                // always mult of 4
        if (gx < 0) gx = 0;
        if (gx > WIDTH - 4) gx = WIDTH - 4;
        const size_t ro = (size_t)gy << 9;
        p = *(const float4*)(P + ro + gx);
        t = *(const float4*)(T + ro + gx);
    };
    auto load_gen = [&](int gybase, float4& p0, float4& t0,
                        float4& p1, float4& t1) {
        ldquad(gybase, erow0, ecq0, p0, t0);
        if (e2) ldquad(gybase, erow1, ecq1, p1, t1);
    };

    auto equad = [&](int gybase, int row, int cq, float4 pv, float4 tv) {
        int gy = gybase + row;
        if ((unsigned)gy >= (unsigned)HEIGHT) {
            pv.x = pv.y = pv.z = pv.w = 0.f;
            tv.x = tv.y = tv.z = tv.w = 0.f;
        } else if (!x_int) {
            int gx0 = x0 - 8 + cq * 4;
            if ((unsigned)(gx0 + 0) >= (unsigned)WIDTH) { pv.x = 0.f; tv.x = 0.f; }
            if ((unsigned)(gx0 + 1) >= (unsigned)WIDTH) { pv.y = 0.f; tv.y = 0.f; }
            if ((unsigned)(gx0 + 2) >= (unsigned)WIDTH) { pv.z = 0.f; tv.z = 0.f; }
            if ((unsigned)(gx0 + 3) >= (unsigned)WIDTH) { pv.w = 0.f; tv.w = 0.f; }
        }
        float u0 = fmaf(pv.x, pv.x, tv.x * tv.x), v0 = pv.x * tv.x;
        float u1 = fmaf(pv.y, pv.y, tv.y * tv.y), v1 = pv.y * tv.y;
        float u2 = fmaf(pv.z, pv.z, tv.z * tv.z), v2 = pv.z * tv.z;
        float u3 = fmaf(pv.w, pv.w, tv.w * tv.w), v3 = pv.w * tv.w;
        uint2 wp, wt, wu, wvv;
        wp.x  = cvt2(pv.x, pv.y); wp.y  = cvt2(pv.z, pv.w);
        wt.x  = cvt2(tv.x, tv.y); wt.y  = cvt2(tv.z, tv.w);
        wu.x  = cvt2(u0, u1);     wu.y  = cvt2(u2, u3);
        wvv.x = cvt2(v0, v1);     wvv.y = cvt2(v2, v3);
        *(uint2*)&s_pl[0][row][cq * 4] = wp;
        *(uint2*)&s_pl[1][row][cq * 4] = wt;
        *(uint2*)&s_pl[2][row][cq * 4] = wu;
        *(uint2*)&s_pl[3][row][cq * 4] = wvv;
    };
    auto ewise = [&](int gybase, float4 p0, float4 t0, float4 p1, float4 t1) {
        equad(gybase, erow0, ecq0, p0, t0);
        if (e2) equad(gybase, erow1, ecq1, p1, t1);
    };

    // h-blur: planes -> sub-tiled ring (transposed). relbase mult of 4:
    // lane writes its 4 D rows (slots s0..s0+3) as one 8B ds_write_b64.
    auto hblur = [&](int relbase) {
        int s0 = relbase + 4 * g4;
        if (s0 >= 96) s0 -= 96; else if (s0 >= 48) s0 -= 48;
        const int sb = s0 >> 3, si = s0 & 7;
        const int acol = (wv << 4) + (g4 << 3);
#pragma unroll
        for (int q = 0; q < 4; ++q) {
            u32x4_t ra = *(const u32x4_t*)&s_pl[q][r15][acol];
            f32x4_t z = {0.f, 0.f, 0.f, 0.f};
            f32x4_t d = __builtin_amdgcn_mfma_f32_16x16x32_f16(
                __builtin_bit_cast(half8_t, ra), Bh, z, 0, 0, 0);
            uint2 pk;
            pk.x = cvt2(d[0], d[1]);
            pk.y = cvt2(d[2], d[3]);
            *(uint2*)&s_ring[q][sb][colA][si] = pk;
        }
    };

    float lsum = 0.f;

    // v-blur + SSIM. Reads rel 16j..16j+31 (k>=26 zero-weight; finite).
    auto vblur = [&](int jstep) {
        int sg = 16 * jstep + (g4 << 3);
        if (sg >= 96) sg -= 96; else if (sg >= 48) sg -= 48;
        const int sb = sg >> 3;              // sg mult of 8: one whole block
        f32x4_t acc[4];
#pragma unroll
        for (int q = 0; q < 4; ++q) {
            u32x4_t ra = *(const u32x4_t*)&s_ring[q][sb][colA][0];
            f32x4_t z = {0.f, 0.f, 0.f, 0.f};
            acc[q] = __builtin_amdgcn_mfma_f32_16x16x32_f16(
                __builtin_bit_cast(half8_t, ra), Bv, z, 0, 0, 0);
        }
#pragma unroll
        for (int r = 0; r < 4; ++r) {
            float mp = acc[0][r], mt = acc[1][r];       // scaled by a
            float U  = acc[2][r], V  = acc[3][r];
            float mpt  = mp * mt;                        // a^2 * true
            float B2   = fmaf(mp, mp, mt * mt);          // a^2 * true
            float S    = fmaf(a, V, -mpt);               // a^2 * sigma_pt
            float Ssum = fmaf(a, U, -B2);                // a^2 * (sp+st)
            float num = fmaf(2.f, mpt, C1A) * fmaf(2.f, S, C2A);
            float den = (B2 + C1A) * (Ssum + C2A);
            lsum += __fdividef(num, den);
        }
    };

    // ---- Prologue (v2 pattern + gen-1 preload for 2-deep) ----
    float4 Ap0, At0, Ap1, At1;      // raw set A (even gens)
    float4 Bp0, Bt0, Bp1, Bt1;      // raw set B (odd gens)
    load_gen(y0 - 5, Ap0, At0, Ap1, At1);   // gen -2: rel 0..15
    load_gen(y0 + 7, Bp0, Bt0, Bp1, Bt1);   // gen -1: rel 12..27
    {
        // zero own wave's 16 columns x 4 qtys (union over wave's lanes);
        // wave-private wrt this wave's vblur reads -> no barrier needed.
        u32x4_t z4 = {0u, 0u, 0u, 0u};
#pragma unroll
        for (int i = 0; i < RING / 8; ++i)
            *(u32x4_t*)&s_ring[g4][i][colA][0] = z4;
    }
    ewise(y0 - 5, Ap0, At0, Ap1, At1);       // planes gen -2
    __syncthreads();
    hblur(0);                                // ring rel 0..15
    load_gen(y0 + 23, Ap0, At0, Ap1, At1);   // gen 0 -> A
    __syncthreads();
    ewise(y0 + 7, Bp0, Bt0, Bp1, Bt1);       // planes gen -1
    __syncthreads();
    hblur(12);                               // ring rel 12..27
    load_gen(y0 + 39, Bp0, Bt0, Bp1, Bt1);   // gen 1 -> B
    __syncthreads();

    // ---- Main loop: 8 steps x 16 output rows, 2 regions per step ----
#pragma unroll 1
    for (int j = 0; j < 8; ++j) {
        // region 1: ewise gen j from set (j&1 ? B : A)
        if (j < 7) {
            if (j & 1) ewise(y0 + 16 * j + 23, Bp0, Bt0, Bp1, Bt1);
            else       ewise(y0 + 16 * j + 23, Ap0, At0, Ap1, At1);
        }
        __syncthreads();
        // region 2: refill the just-freed set with gen j+2 (pinned here by
        // the surrounding barriers; consumed at region 1 of step j+2),
        // then h-blur gen j and v-blur step j.
        if (j < 5) {
            if (j & 1) load_gen(y0 + 16 * (j + 2) + 23, Bp0, Bt0, Bp1, Bt1);
            else       load_gen(y0 + 16 * (j + 2) + 23, Ap0, At0, Ap1, At1);
        }
        if (j < 7) hblur(16 * j + 28);       // rel 16j+28..43 (own columns)
        vblur(j);                            // reads rel 16j..16j+31
        __syncthreads();
    }

    // ---- Block reduction -> one partial per block ----
#pragma unroll
    for (int off = 32; off > 0; off >>= 1) lsum += __shfl_down(lsum, off);
    if ((tid & 63) == 0) s_red[tid >> 6] = lsum;
    __syncthreads();
    if (tid == 0) {
        partial[(blockIdx.z * TILES_Y + blockIdx.y) * TILES_X + blockIdx.x] =
            s_red[0] + s_red[1] + s_red[2] + s_red[3];
    }
}

__global__ __launch_bounds__(256)
void ssim_final(const float* __restrict__ partial, float* __restrict__ out) {
    __shared__ float s_red[4];
    float s = 0.f;
    for (int i = threadIdx.x; i < NBLK; i += 256) s += partial[i];
#pragma unroll
    for (int off = 32; off > 0; off >>= 1) s += __shfl_down(s, off);
    if ((threadIdx.x & 63) == 0) s_red[threadIdx.x >> 6] = s;
    __syncthreads();
    if (threadIdx.x == 0) {
        float total = s_red[0] + s_red[1] + s_red[2] + s_red[3];
        out[0] = 1.0f - total / NPIXF;
    }
}

extern "C" void kernel_launch(void* const* d_in, const int* in_sizes, int n_in,
                              void* d_out, int out_size, void* d_ws, size_t ws_size,
                              hipStream_t stream) {
    const float* pred = (const float*)d_in[0];
    const float* tgt  = (const float*)d_in[1];
    float* partial = (float*)d_ws;   // NBLK floats, fully rewritten each call

    dim3 grid(TILES_X, TILES_Y, PLANES);
    ssim_main<<<grid, dim3(256), 0, stream>>>(pred, tgt, partial);
    ssim_final<<<1, dim3(256), 0, stream>>>(partial, (float*)d_out);
}